// Round 3
// baseline (641.547 us; speedup 1.0000x reference)
//
#include <hip/hip_runtime.h>
#include <hip/hip_bf16.h>
#include <stdint.h>

#define D_MODEL 2048
#define D_FF    8192
#define NTOK    4096
#define WSCALE  0.02f

using bf16 = __hip_bfloat16;
typedef __bf16 bf16x8 __attribute__((ext_vector_type(8)));
typedef float  f32x4  __attribute__((ext_vector_type(4)));

// async global -> LDS, 16 B per lane (wave-uniform base + lane*16 layout)
__device__ __forceinline__ void gld_lds16(const bf16* g, bf16* l) {
    __builtin_amdgcn_global_load_lds((const __attribute__((address_space(1))) void*)g,
                                     (__attribute__((address_space(3))) void*)l,
                                     16, 0, 0);
}

// ---------------- standalone dequant (fallback when ws can't hold separate Wd) --------------
__global__ __launch_bounds__(256) void dequant_kernel(const int* __restrict__ walks,
                                                      const float* __restrict__ lut,
                                                      const float* __restrict__ sl,
                                                      const float* __restrict__ sr,
                                                      bf16* __restrict__ W,
                                                      int colsLog2) {
    __shared__ float slut[256];
    slut[threadIdx.x] = lut[threadIdx.x] * WSCALE;
    __syncthreads();
    long base = ((long)blockIdx.x * 256 + threadIdx.x) * 8;
    int r = (int)(base >> colsLog2);
    int c = (int)(base & ((1 << colsLog2) - 1));
    float s = sl[r];
    const int4* wp = (const int4*)(walks + base);
    int4 w0 = wp[0];
    int4 w1 = wp[1];
    float4 s0 = *(const float4*)(sr + c);
    float4 s1 = *(const float4*)(sr + c + 4);
    alignas(16) bf16 o[8];
    o[0] = __float2bfloat16(slut[w0.x] * s0.x * s);
    o[1] = __float2bfloat16(slut[w0.y] * s0.y * s);
    o[2] = __float2bfloat16(slut[w0.z] * s0.z * s);
    o[3] = __float2bfloat16(slut[w0.w] * s0.w * s);
    o[4] = __float2bfloat16(slut[w1.x] * s1.x * s);
    o[5] = __float2bfloat16(slut[w1.y] * s1.y * s);
    o[6] = __float2bfloat16(slut[w1.z] * s1.z * s);
    o[7] = __float2bfloat16(slut[w1.w] * s1.w * s);
    *(uint4*)(W + base) = *(const uint4*)o;
}

// ---------------- merged prep: x->bf16 + up to 3 dequants, one launch ----------------
__global__ __launch_bounds__(256) void prep_kernel(const float* __restrict__ x, bf16* __restrict__ xb,
    const int* __restrict__ wk_g, const float* __restrict__ lut_g,
    const float* __restrict__ sl_g, const float* __restrict__ sr_g, bf16* __restrict__ Wg,
    const int* __restrict__ wk_u, const float* __restrict__ lut_u,
    const float* __restrict__ sl_u, const float* __restrict__ sr_u, bf16* __restrict__ Wu,
    const int* __restrict__ wk_d, const float* __restrict__ lut_d,
    const float* __restrict__ sl_d, const float* __restrict__ sr_d, bf16* __restrict__ Wd) {
    const int t = threadIdx.x;
    const int b = blockIdx.x;
    if (b < 4096) {
        long base = ((long)b * 256 + t) * 8;
        float4 a = *(const float4*)(x + base);
        float4 v = *(const float4*)(x + base + 4);
        alignas(16) bf16 o[8];
        o[0] = __float2bfloat16(a.x); o[1] = __float2bfloat16(a.y);
        o[2] = __float2bfloat16(a.z); o[3] = __float2bfloat16(a.w);
        o[4] = __float2bfloat16(v.x); o[5] = __float2bfloat16(v.y);
        o[6] = __float2bfloat16(v.z); o[7] = __float2bfloat16(v.w);
        *(uint4*)(xb + base) = *(const uint4*)o;
        return;
    }
    const int* wk; const float* lut; const float* sl; const float* sr; bf16* W;
    int clog, bb;
    if (b < 12288)      { wk = wk_g; lut = lut_g; sl = sl_g; sr = sr_g; W = Wg; clog = 11; bb = b - 4096; }
    else if (b < 20480) { wk = wk_u; lut = lut_u; sl = sl_u; sr = sr_u; W = Wu; clog = 11; bb = b - 12288; }
    else                { wk = wk_d; lut = lut_d; sl = sl_d; sr = sr_d; W = Wd; clog = 13; bb = b - 20480; }
    __shared__ float slut[256];
    slut[t] = lut[t] * WSCALE;
    __syncthreads();
    long base = ((long)bb * 256 + t) * 8;
    int r = (int)(base >> clog);
    int c = (int)(base & ((1 << clog) - 1));
    float s = sl[r];
    const int4* wp = (const int4*)(wk + base);
    int4 w0 = wp[0];
    int4 w1 = wp[1];
    float4 s0 = *(const float4*)(sr + c);
    float4 s1 = *(const float4*)(sr + c + 4);
    alignas(16) bf16 o[8];
    o[0] = __float2bfloat16(slut[w0.x] * s0.x * s);
    o[1] = __float2bfloat16(slut[w0.y] * s0.y * s);
    o[2] = __float2bfloat16(slut[w0.z] * s0.z * s);
    o[3] = __float2bfloat16(slut[w0.w] * s0.w * s);
    o[4] = __float2bfloat16(slut[w1.x] * s1.x * s);
    o[5] = __float2bfloat16(slut[w1.y] * s1.y * s);
    o[6] = __float2bfloat16(slut[w1.z] * s1.z * s);
    o[7] = __float2bfloat16(slut[w1.w] * s1.w * s);
    *(uint4*)(W + base) = *(const uint4*)o;
}

// LDS XOR swizzle, BK=64 (8 chunks of 8 bf16 per 128 B row): chunk c of row r at
// slot (c + r) & 7. Writer: linear LDS dest, inverse-swizzled GLOBAL source (colO).
// Reader: s0 = ((lane>>4)+(m16&7))&7 slot; ks=1 slot = slot^4 via sx = (s0^32)-s0.
//
// R3 sync structure (post-mortem of R2's 50% MfmaUtil): two barriers per K-tile.
//   M (mid-tile): vmcnt(0) [only stage(t+1) outstanding, issued a full tile ago]
//     + s_barrier -> next buffer valid; IMMEDIATELY read next tile's first-cluster
//     operands into the SAME registers as the (now dead) a0/g0 -> the next tile's
//     first MFMA cluster has its ds_reads in service across E + loop-back: no
//     exposed LDS head at barrier exit (R2's ~585 cyc/tile loss).
//   E (end): s_barrier -> all waves' reads of cur buffer done; only THEN issue
//     stage(t+2) into it. This also fixes R2's latent WAR race (staging was issued
//     before reads of the target buffer were globally complete).
// All lgkm waits are compiler-counted (no lgkm asm anywhere -- R1 lesson).
// NOTE: epilogue acc loops MUST stay fully unrolled — runtime idx -> scratch spill.

// ---------------- fused gate+up GEMM, 256x128 tile, BK=64 ----------------
__global__ __launch_bounds__(512, 2) void gemm_gateup(const bf16* __restrict__ A,
                                                      const bf16* __restrict__ Bg_,
                                                      const bf16* __restrict__ Bu_,
                                                      bf16* __restrict__ G) {
    __shared__ alignas(16) char smem[131072];
    bf16* As  = (bf16*)smem;                 // [2][256][64] : 2 x 32 KB
    bf16* Bgs = (bf16*)(smem + 65536);       // [2][128][64] : 2 x 16 KB
    bf16* Bus = (bf16*)(smem + 98304);       // [2][128][64] : 2 x 16 KB

    const int t = threadIdx.x;
    const int mBase = blockIdx.y * 256;
    const int nBase = blockIdx.x * 128;
    const int K = D_MODEL;
    const int NT = K / 64;                   // 32 K-tiles

    const int srow = t >> 3;                                  // 0..63 (64 rows per pass)
    const int colO = (((t & 7) - (srow & 7)) & 7) * 8;        // pre-swizzled global chunk
    const bf16* Ag  = A   + (long)(mBase + srow) * K + colO;
    const bf16* Bgg = Bg_ + (long)(nBase + srow) * K + colO;
    const bf16* Bug = Bu_ + (long)(nBase + srow) * K + colO;
    const long rstep = (long)64 * K;

    f32x4 accg[4][4], accu[4][4];
#pragma unroll
    for (int i = 0; i < 4; i++)
#pragma unroll
        for (int j = 0; j < 4; j++) {
            f32x4 z = {0.f, 0.f, 0.f, 0.f};
            accg[i][j] = z; accu[i][j] = z;
        }

    const int lane  = t & 63;
    const int wave  = t >> 6;                 // 0..7
    const int waveM = (wave >> 1) * 64;       // 0,64,128,192
    const int waveN = (wave & 1) * 64;        // 0,64
    const int m16   = lane & 15;
    const int s0    = (((lane >> 4) + (m16 & 7)) & 7) * 8;
    const int sx    = (s0 ^ 32) - s0;         // chunk+4 (mod 8) for ks=1

    const bf16* Asr0 = As  + (waveM + m16) * 64 + s0;
    const bf16* Bgr0 = Bgs + (waveN + m16) * 64 + s0;
    const bf16* Bur0 = Bus + (waveN + m16) * 64 + s0;

    bf16* Asw = As  + t * 8;
    bf16* Bgw = Bgs + t * 8;
    bf16* Buw = Bus + t * 8;

    // prologue: stage tile 0 -> buf0, tile 1 -> buf1 (16 loads outstanding)
#pragma unroll
    for (int p = 0; p < 4; p++) gld_lds16(Ag  + p * rstep, Asw + p * 4096);
#pragma unroll
    for (int p = 0; p < 2; p++) gld_lds16(Bgg + p * rstep, Bgw + p * 4096);
#pragma unroll
    for (int p = 0; p < 2; p++) gld_lds16(Bug + p * rstep, Buw + p * 4096);
#pragma unroll
    for (int p = 0; p < 4; p++) gld_lds16(Ag  + 64 + p * rstep, Asw + 16384 + p * 4096);
#pragma unroll
    for (int p = 0; p < 2; p++) gld_lds16(Bgg + 64 + p * rstep, Bgw + 8192 + p * 4096);
#pragma unroll
    for (int p = 0; p < 2; p++) gld_lds16(Bug + 64 + p * rstep, Buw + 8192 + p * 4096);
    asm volatile("s_waitcnt vmcnt(8)" ::: "memory");   // tile 0's 8 (oldest) done
    __builtin_amdgcn_s_barrier();

    bf16x8 af[4], gf[4];                      // persist across iterations (reused regs)
    {
        const bf16* ar = Asr0;
        const bf16* gr = Bgr0;
#pragma unroll
        for (int i = 0; i < 4; i++) af[i] = *(const bf16x8*)(ar + i * 1024);
#pragma unroll
        for (int j = 0; j < 4; j++) gf[j] = *(const bf16x8*)(gr + j * 1024);
    }

    int c = 0;
    for (int tI = 0; tI < NT; ++tI) {
        const bf16* ar = Asr0 + c * 16384;
        const bf16* gr = Bgr0 + c * 8192;
        const bf16* ur = Bur0 + c * 8192;
        const int cn = c ^ 1;

        bf16x8 uf[4], a1[4], g1[4], u1[4];
        // group 1: u0, a1 (cluster G0's operands already in af/gf)
#pragma unroll
        for (int j = 0; j < 4; j++) uf[j] = *(const bf16x8*)(ur + j * 1024);
#pragma unroll
        for (int i = 0; i < 4; i++) a1[i] = *(const bf16x8*)(ar + sx + i * 1024);

        __builtin_amdgcn_s_setprio(1);
#pragma unroll
        for (int i = 0; i < 4; i++)
#pragma unroll
            for (int j = 0; j < 4; j++)
                accg[i][j] = __builtin_amdgcn_mfma_f32_16x16x32_bf16(af[i], gf[j], accg[i][j], 0, 0, 0);
        __builtin_amdgcn_s_setprio(0);

        // group 2: g1, u1
#pragma unroll
        for (int j = 0; j < 4; j++) g1[j] = *(const bf16x8*)(gr + sx + j * 1024);
#pragma unroll
        for (int j = 0; j < 4; j++) u1[j] = *(const bf16x8*)(ur + sx + j * 1024);

        __builtin_amdgcn_s_setprio(1);
#pragma unroll
        for (int i = 0; i < 4; i++)
#pragma unroll
            for (int j = 0; j < 4; j++)
                accu[i][j] = __builtin_amdgcn_mfma_f32_16x16x32_bf16(af[i], uf[j], accu[i][j], 0, 0, 0);
        __builtin_amdgcn_s_setprio(0);

        if (tI + 1 < NT) {
            // M barrier: stage(t+1) is the only outstanding VMEM (issued a tile ago)
            asm volatile("s_waitcnt vmcnt(0)" ::: "memory");
            __builtin_amdgcn_s_barrier();
            // cross-barrier read-ahead: next tile's first cluster, reusing af/gf regs
            const bf16* arn = Asr0 + cn * 16384;
            const bf16* grn = Bgr0 + cn * 8192;
#pragma unroll
            for (int i = 0; i < 4; i++) af[i] = *(const bf16x8*)(arn + i * 1024);
#pragma unroll
            for (int j = 0; j < 4; j++) gf[j] = *(const bf16x8*)(grn + j * 1024);
        }

        __builtin_amdgcn_s_setprio(1);
#pragma unroll
        for (int i = 0; i < 4; i++)
#pragma unroll
            for (int j = 0; j < 4; j++)
                accg[i][j] = __builtin_amdgcn_mfma_f32_16x16x32_bf16(a1[i], g1[j], accg[i][j], 0, 0, 0);
#pragma unroll
        for (int i = 0; i < 4; i++)
#pragma unroll
            for (int j = 0; j < 4; j++)
                accu[i][j] = __builtin_amdgcn_mfma_f32_16x16x32_bf16(a1[i], u1[j], accu[i][j], 0, 0, 0);
        __builtin_amdgcn_s_setprio(0);

        if (tI + 2 < NT) {
            // E barrier: all waves done reading buf[c] -> safe to restage it
            __builtin_amdgcn_s_barrier();
            bf16* aw = Asw + c * 16384;
            bf16* gw = Bgw + c * 8192;
            bf16* uw = Buw + c * 8192;
            const int kn = (tI + 2) * 64;
#pragma unroll
            for (int p = 0; p < 4; p++) gld_lds16(Ag  + kn + p * rstep, aw + p * 4096);
#pragma unroll
            for (int p = 0; p < 2; p++) gld_lds16(Bgg + kn + p * rstep, gw + p * 4096);
#pragma unroll
            for (int p = 0; p < 2; p++) gld_lds16(Bug + kn + p * rstep, uw + p * 4096);
        }

        c = cn;
    }

    // epilogue: per-wave LDS transpose -> silu(g)*u -> coalesced bf16 stores
    __syncthreads();
    float* Tw = (float*)smem + wave * 1088;
    const int rq = (lane >> 4) * 4;
#pragma unroll
    for (int i = 0; i < 4; i++) {
#pragma unroll
        for (int j = 0; j < 4; j++)
#pragma unroll
            for (int r = 0; r < 4; r++) {
                float g = accg[i][j][r];
                float u = accu[i][j][r];
                float h = (g / (1.0f + __expf(-g))) * u;
                Tw[(rq + r) * 68 + j * 16 + m16] = h;
            }
        __syncthreads();
#pragma unroll
        for (int s = 0; s < 4; s++) {
            int row = (lane >> 4) + 4 * s;
            f32x4 v = *(const f32x4*)(Tw + row * 68 + (m16 << 2));
            union { ushort u16[4]; uint2 d; } o;
            o.u16[0] = __bfloat16_as_ushort(__float2bfloat16(v[0]));
            o.u16[1] = __bfloat16_as_ushort(__float2bfloat16(v[1]));
            o.u16[2] = __bfloat16_as_ushort(__float2bfloat16(v[2]));
            o.u16[3] = __bfloat16_as_ushort(__float2bfloat16(v[3]));
            long grow = mBase + waveM + i * 16 + row;
            int  gcol = nBase + waveN + (m16 << 2);
            *(uint2*)(G + grow * D_FF + gcol) = o.d;
        }
        __syncthreads();
    }
}

// ---------------- down GEMM: Out[4096, 2048] = G @ Wd^T, fp32 out ----------------
// Same R3 structure: BK=64 dbuf (64 KiB LDS, 2 blocks/CU), 8-slot XOR swizzle,
// M barrier (vmcnt(0)) + cross-barrier read-ahead into reused a0/b0 regs, E barrier
// before restaging.
__global__ __launch_bounds__(256, 2) void gemm_down(const bf16* __restrict__ A,
                                                    const bf16* __restrict__ B,
                                                    float* __restrict__ Out) {
    __shared__ alignas(16) char smem[65536];   // A: 2x16KB, B: 2x16KB; epilogue T = 17408 B
    bf16* As = (bf16*)smem;                    // [2][128][64]
    bf16* Bs = (bf16*)(smem + 32768);          // [2][128][64]

    const int t = threadIdx.x;
    const int mBase = blockIdx.y * 128;
    const int nBase = blockIdx.x * 128;
    const int K = D_FF;
    const int NT = K / 64;                     // 128 K-tiles

    const int srow = t >> 3;                                  // 0..31 (32 rows per pass)
    const int colO = (((t & 7) - (srow & 7)) & 7) * 8;        // pre-swizzled global chunk
    const bf16* Ag = A + (long)(mBase + srow) * K + colO;
    const bf16* Bg = B + (long)(nBase + srow) * K + colO;
    const long rstep = (long)32 * K;

    f32x4 acc[4][4];
#pragma unroll
    for (int i = 0; i < 4; i++)
#pragma unroll
        for (int j = 0; j < 4; j++) {
            f32x4 z = {0.f, 0.f, 0.f, 0.f};
            acc[i][j] = z;
        }

    const int lane  = t & 63;
    const int wave  = t >> 6;                 // 0..3
    const int waveM = (wave & 1) * 64;
    const int waveN = (wave >> 1) * 64;
    const int m16   = lane & 15;
    const int s0    = (((lane >> 4) + (m16 & 7)) & 7) * 8;
    const int sx    = (s0 ^ 32) - s0;

    const bf16* Asr0 = As + (waveM + m16) * 64 + s0;
    const bf16* Bsr0 = Bs + (waveN + m16) * 64 + s0;

    bf16* Asw = As + t * 8;
    bf16* Bsw = Bs + t * 8;

    // prologue: stage tile 0 -> buf0, tile 1 -> buf1
#pragma unroll
    for (int p = 0; p < 4; p++) gld_lds16(Ag + p * rstep, Asw + p * 2048);
#pragma unroll
    for (int p = 0; p < 4; p++) gld_lds16(Bg + p * rstep, Bsw + p * 2048);
#pragma unroll
    for (int p = 0; p < 4; p++) gld_lds16(Ag + 64 + p * rstep, Asw + 8192 + p * 2048);
#pragma unroll
    for (int p = 0; p < 4; p++) gld_lds16(Bg + 64 + p * rstep, Bsw + 8192 + p * 2048);
    asm volatile("s_waitcnt vmcnt(8)" ::: "memory");
    __builtin_amdgcn_s_barrier();

    bf16x8 a0[4], b0[4];                      // persist across iterations (reused regs)
    {
#pragma unroll
        for (int i = 0; i < 4; i++) a0[i] = *(const bf16x8*)(Asr0 + i * 1024);
#pragma unroll
        for (int j = 0; j < 4; j++) b0[j] = *(const bf16x8*)(Bsr0 + j * 1024);
    }

    int c = 0;
    for (int tI = 0; tI < NT; ++tI) {
        const bf16* ar = Asr0 + c * 8192;
        const bf16* br = Bsr0 + c * 8192;
        const int cn = c ^ 1;

        bf16x8 a1[4], b1[4];
#pragma unroll
        for (int i = 0; i < 4; i++) a1[i] = *(const bf16x8*)(ar + sx + i * 1024);
#pragma unroll
        for (int j = 0; j < 4; j++) b1[j] = *(const bf16x8*)(br + sx + j * 1024);

        __builtin_amdgcn_s_setprio(1);
#pragma unroll
        for (int i = 0; i < 4; i++)
#pragma unroll
            for (int j = 0; j < 4; j++)
                acc[i][j] = __builtin_amdgcn_mfma_f32_16x16x32_bf16(a0[i], b0[j], acc[i][j], 0, 0, 0);
        __builtin_amdgcn_s_setprio(0);

        if (tI + 1 < NT) {
            asm volatile("s_waitcnt vmcnt(0)" ::: "memory");
            __builtin_amdgcn_s_barrier();                     // M: next buffer valid
            const bf16* arn = Asr0 + cn * 8192;
            const bf16* brn = Bsr0 + cn * 8192;
#pragma unroll
            for (int i = 0; i < 4; i++) a0[i] = *(const bf16x8*)(arn + i * 1024);
#pragma unroll
            for (int j = 0; j < 4; j++) b0[j] = *(const bf16x8*)(brn + j * 1024);
        }

        __builtin_amdgcn_s_setprio(1);
#pragma unroll
        for (int i = 0; i < 4; i++)
#pragma unroll
            for (int j = 0; j < 4; j++)
                acc[i][j] = __builtin_amdgcn_mfma_f32_16x16x32_bf16(a1[i], b1[j], acc[i][j], 0, 0, 0);
        __builtin_amdgcn_s_setprio(0);

        if (tI + 2 < NT) {
            __builtin_amdgcn_s_barrier();                     // E: buf[c] free
            bf16* aw = Asw + c * 8192;
            bf16* bw = Bsw + c * 8192;
            const int kn = (tI + 2) * 64;
#pragma unroll
            for (int p = 0; p < 4; p++) gld_lds16(Ag + kn + p * rstep, aw + p * 2048);
#pragma unroll
            for (int p = 0; p < 4; p++) gld_lds16(Bg + kn + p * rstep, bw + p * 2048);
        }

        c = cn;
    }

    // epilogue: per-wave LDS transpose -> coalesced f32x4 stores (256 B segments)
    __syncthreads();
    float* Tw = (float*)smem + wave * 1088;
    const int rq = (lane >> 4) * 4;
#pragma unroll
    for (int i = 0; i < 4; i++) {
#pragma unroll
        for (int j = 0; j < 4; j++)
#pragma unroll
            for (int r = 0; r < 4; r++)
                Tw[(rq + r) * 68 + j * 16 + m16] = acc[i][j][r];
        __syncthreads();
#pragma unroll
        for (int s = 0; s < 4; s++) {
            int row = (lane >> 4) + 4 * s;
            f32x4 v = *(const f32x4*)(Tw + row * 68 + (m16 << 2));
            long grow = mBase + waveM + i * 16 + row;
            int  gcol = nBase + waveN + (m16 << 2);
            *(f32x4*)(Out + grow * D_MODEL + gcol) = v;
        }
        __syncthreads();
    }
}

extern "C" void kernel_launch(void* const* d_in, const int* in_sizes, int n_in,
                              void* d_out, int out_size, void* d_ws, size_t ws_size,
                              hipStream_t stream) {
    (void)in_sizes; (void)n_in; (void)out_size;
    const float* x     = (const float*)d_in[0];
    const float* lut_g = (const float*)d_in[1];
    const float* lut_u = (const float*)d_in[2];
    const float* lut_d = (const float*)d_in[3];
    const int*   wk_g  = (const int*)d_in[4];
    const int*   wk_u  = (const int*)d_in[5];
    const int*   wk_d  = (const int*)d_in[6];
    const float* sl_g  = (const float*)d_in[7];
    const float* sr_g  = (const float*)d_in[8];
    const float* sl_u  = (const float*)d_in[9];
    const float* sr_u  = (const float*)d_in[10];
    const float* sl_d  = (const float*)d_in[11];
    const float* sr_d  = (const float*)d_in[12];

    char* ws = (char*)d_ws;
    bf16* xb = (bf16*)(ws);                                   // 16 MB
    bf16* Wg = (bf16*)(ws + (size_t)16 * 1024 * 1024);        // 32 MB
    bf16* Wu = (bf16*)(ws + (size_t)48 * 1024 * 1024);        // 32 MB
    bf16* G  = (bf16*)(ws + (size_t)80 * 1024 * 1024);        // 64 MB
    const bool sepWd = ws_size >= (size_t)176 * 1024 * 1024;
    bf16* Wd = sepWd ? (bf16*)(ws + (size_t)144 * 1024 * 1024) : Wg;
    float* out = (float*)d_out;

    prep_kernel<<<dim3(sepWd ? 28672 : 20480), 256, 0, stream>>>(
        x, xb, wk_g, lut_g, sl_g, sr_g, Wg, wk_u, lut_u, sl_u, sr_u, Wu,
        wk_d, lut_d, sl_d, sr_d, sepWd ? Wd : nullptr);

    gemm_gateup<<<dim3(D_FF / 128, NTOK / 256), 512, 0, stream>>>(xb, Wg, Wu, G);

    if (!sepWd)
        dequant_kernel<<<dim3(D_MODEL * D_FF / 2048), 256, 0, stream>>>(wk_d, lut_d, sl_d, sr_d, Wd, 13);

    gemm_down<<<dim3(D_MODEL / 128, NTOK / 128), 256, 0, stream>>>(G, Wd, out);
}

// Round 4
// 604.237 us; speedup vs baseline: 1.0617x; 1.0617x over previous
//
#include <hip/hip_runtime.h>
#include <hip/hip_bf16.h>
#include <stdint.h>

#define D_MODEL 2048
#define D_FF    8192
#define NTOK    4096
#define WSCALE  0.02f

using bf16 = __hip_bfloat16;
typedef __bf16 bf16x8 __attribute__((ext_vector_type(8)));
typedef float  f32x4  __attribute__((ext_vector_type(4)));

// async global -> LDS, 16 B per lane (wave-uniform base + lane*16 layout)
__device__ __forceinline__ void gld_lds16(const bf16* g, bf16* l) {
    __builtin_amdgcn_global_load_lds((const __attribute__((address_space(1))) void*)g,
                                     (__attribute__((address_space(3))) void*)l,
                                     16, 0, 0);
}

// ---------------- standalone dequant (fallback when ws can't hold separate Wd) --------------
__global__ __launch_bounds__(256) void dequant_kernel(const int* __restrict__ walks,
                                                      const float* __restrict__ lut,
                                                      const float* __restrict__ sl,
                                                      const float* __restrict__ sr,
                                                      bf16* __restrict__ W,
                                                      int colsLog2) {
    __shared__ float slut[256];
    slut[threadIdx.x] = lut[threadIdx.x] * WSCALE;
    __syncthreads();
    long base = ((long)blockIdx.x * 256 + threadIdx.x) * 8;
    int r = (int)(base >> colsLog2);
    int c = (int)(base & ((1 << colsLog2) - 1));
    float s = sl[r];
    const int4* wp = (const int4*)(walks + base);
    int4 w0 = wp[0];
    int4 w1 = wp[1];
    float4 s0 = *(const float4*)(sr + c);
    float4 s1 = *(const float4*)(sr + c + 4);
    alignas(16) bf16 o[8];
    o[0] = __float2bfloat16(slut[w0.x] * s0.x * s);
    o[1] = __float2bfloat16(slut[w0.y] * s0.y * s);
    o[2] = __float2bfloat16(slut[w0.z] * s0.z * s);
    o[3] = __float2bfloat16(slut[w0.w] * s0.w * s);
    o[4] = __float2bfloat16(slut[w1.x] * s1.x * s);
    o[5] = __float2bfloat16(slut[w1.y] * s1.y * s);
    o[6] = __float2bfloat16(slut[w1.z] * s1.z * s);
    o[7] = __float2bfloat16(slut[w1.w] * s1.w * s);
    *(uint4*)(W + base) = *(const uint4*)o;
}

// ---------------- merged prep: x->bf16 + up to 3 dequants, one launch ----------------
__global__ __launch_bounds__(256) void prep_kernel(const float* __restrict__ x, bf16* __restrict__ xb,
    const int* __restrict__ wk_g, const float* __restrict__ lut_g,
    const float* __restrict__ sl_g, const float* __restrict__ sr_g, bf16* __restrict__ Wg,
    const int* __restrict__ wk_u, const float* __restrict__ lut_u,
    const float* __restrict__ sl_u, const float* __restrict__ sr_u, bf16* __restrict__ Wu,
    const int* __restrict__ wk_d, const float* __restrict__ lut_d,
    const float* __restrict__ sl_d, const float* __restrict__ sr_d, bf16* __restrict__ Wd) {
    const int t = threadIdx.x;
    const int b = blockIdx.x;
    if (b < 4096) {
        long base = ((long)b * 256 + t) * 8;
        float4 a = *(const float4*)(x + base);
        float4 v = *(const float4*)(x + base + 4);
        alignas(16) bf16 o[8];
        o[0] = __float2bfloat16(a.x); o[1] = __float2bfloat16(a.y);
        o[2] = __float2bfloat16(a.z); o[3] = __float2bfloat16(a.w);
        o[4] = __float2bfloat16(v.x); o[5] = __float2bfloat16(v.y);
        o[6] = __float2bfloat16(v.z); o[7] = __float2bfloat16(v.w);
        *(uint4*)(xb + base) = *(const uint4*)o;
        return;
    }
    const int* wk; const float* lut; const float* sl; const float* sr; bf16* W;
    int clog, bb;
    if (b < 12288)      { wk = wk_g; lut = lut_g; sl = sl_g; sr = sr_g; W = Wg; clog = 11; bb = b - 4096; }
    else if (b < 20480) { wk = wk_u; lut = lut_u; sl = sl_u; sr = sr_u; W = Wu; clog = 11; bb = b - 12288; }
    else                { wk = wk_d; lut = lut_d; sl = sl_d; sr = sr_d; W = Wd; clog = 13; bb = b - 20480; }
    __shared__ float slut[256];
    slut[t] = lut[t] * WSCALE;
    __syncthreads();
    long base = ((long)bb * 256 + t) * 8;
    int r = (int)(base >> clog);
    int c = (int)(base & ((1 << clog) - 1));
    float s = sl[r];
    const int4* wp = (const int4*)(wk + base);
    int4 w0 = wp[0];
    int4 w1 = wp[1];
    float4 s0 = *(const float4*)(sr + c);
    float4 s1 = *(const float4*)(sr + c + 4);
    alignas(16) bf16 o[8];
    o[0] = __float2bfloat16(slut[w0.x] * s0.x * s);
    o[1] = __float2bfloat16(slut[w0.y] * s0.y * s);
    o[2] = __float2bfloat16(slut[w0.z] * s0.z * s);
    o[3] = __float2bfloat16(slut[w0.w] * s0.w * s);
    o[4] = __float2bfloat16(slut[w1.x] * s1.x * s);
    o[5] = __float2bfloat16(slut[w1.y] * s1.y * s);
    o[6] = __float2bfloat16(slut[w1.z] * s1.z * s);
    o[7] = __float2bfloat16(slut[w1.w] * s1.w * s);
    *(uint4*)(W + base) = *(const uint4*)o;
}

// LDS XOR swizzle, BK=64 (8 chunks of 8 bf16 per 128 B row):
//   chunk c of row r at slot (c + r) & 7.  Writer: linear LDS dest, inverse-swizzled
//   GLOBAL source (colO).  Reader: s0 = ((lane>>4)+(m16&7))&7 slot; ks=1 slot = slot^4
//   via sx = (s0^32)-s0.
//
// Sync structure = R2 (best measured: 50% MfmaUtil): counted vmcnt(8) dbuf,
// ONE barrier + ZERO lgkm asm per K-tile; fragment loads in prefetch order,
// compiler-counted lgkm waits. (R1's per-phase lgkmcnt(0) lockstep and R3's
// E-barrier/stage-at-end both regressed — do not reintroduce.)
//
// R4 adds ONLY the XCD-aware block swizzle (T1). Evidence: both GEMMs converge
// at ~12-14 B/cyc/CU fetch service (gateup 128KB/CU-tile over 9336 cyc; down
// 64KB over 5443 cyc) -> L2-fill bound via ~8x XCD duplication of shared panels.
// gateup: same-bx blocks (share the 64MB Wg/Wu panels) go co-XCD;
// down:   same-by blocks (share the 64MB G panels) go co-XCD.
// Both grids %8 == 0 -> simple bijective chunked remap.
// NOTE: epilogue acc loops MUST stay fully unrolled — runtime idx -> scratch spill.

// ---------------- fused gate+up GEMM, 256x128 tile, BK=64, 1-barrier pipelined K-tile -------
__global__ __launch_bounds__(512, 2) void gemm_gateup(const bf16* __restrict__ A,
                                                      const bf16* __restrict__ Bg_,
                                                      const bf16* __restrict__ Bu_,
                                                      bf16* __restrict__ G) {
    __shared__ alignas(16) char smem[131072];
    bf16* As  = (bf16*)smem;                 // [2][256][64] : 2 x 32 KB
    bf16* Bgs = (bf16*)(smem + 65536);       // [2][128][64] : 2 x 16 KB
    bf16* Bus = (bf16*)(smem + 98304);       // [2][128][64] : 2 x 16 KB

    const int t = threadIdx.x;
    // XCD swizzle: nwg = 64x16 = 1024, 128 blocks per XCD chunk. Within an XCD the
    // work index w walks (bx fixed-range, by fastest): bx = w>>4 in [8k, 8k+8),
    // by = w&15 -> the 16 blocks sharing each Wg/Wu panel are co-XCD.
    {
    }
    const int o_ = blockIdx.y * 64 + blockIdx.x;
    const int w_ = (o_ & 7) * 128 + (o_ >> 3);
    const int mBase = (w_ & 15) * 256;       // by
    const int nBase = (w_ >> 4) * 128;       // bx
    const int K = D_MODEL;

    const int srow = t >> 3;                                  // 0..63 (64 rows per pass)
    const int colO = (((t & 7) - (srow & 7)) & 7) * 8;        // pre-swizzled global chunk
    const bf16* Ag  = A   + (long)(mBase + srow) * K + colO;
    const bf16* Bgg = Bg_ + (long)(nBase + srow) * K + colO;
    const bf16* Bug = Bu_ + (long)(nBase + srow) * K + colO;
    const long rstep = (long)64 * K;

    f32x4 accg[4][4], accu[4][4];
#pragma unroll
    for (int i = 0; i < 4; i++)
#pragma unroll
        for (int j = 0; j < 4; j++) {
            f32x4 z = {0.f, 0.f, 0.f, 0.f};
            accg[i][j] = z; accu[i][j] = z;
        }

    const int lane  = t & 63;
    const int wave  = t >> 6;                 // 0..7
    const int waveM = (wave >> 1) * 64;       // 0,64,128,192
    const int waveN = (wave & 1) * 64;        // 0,64
    const int m16   = lane & 15;
    const int s0    = (((lane >> 4) + (m16 & 7)) & 7) * 8;
    const int sx    = (s0 ^ 32) - s0;         // chunk+4 (mod 8) for ks=1

    const bf16* Asr0 = As  + (waveM + m16) * 64 + s0;
    const bf16* Bgr0 = Bgs + (waveN + m16) * 64 + s0;
    const bf16* Bur0 = Bus + (waveN + m16) * 64 + s0;

    bf16* Asw = As  + t * 8;
    bf16* Bgw = Bgs + t * 8;
    bf16* Buw = Bus + t * 8;

    // prologue: stage K-tile 0 into buffer 0 (8 loads)
#pragma unroll
    for (int p = 0; p < 4; p++) gld_lds16(Ag  + p * rstep, Asw + p * 4096);
#pragma unroll
    for (int p = 0; p < 2; p++) gld_lds16(Bgg + p * rstep, Bgw + p * 4096);
#pragma unroll
    for (int p = 0; p < 2; p++) gld_lds16(Bug + p * rstep, Buw + p * 4096);

    int c = 0;
    for (int k0 = 0; k0 < K; k0 += 64) {
        if (k0 + 64 < K) {
            // stage next K-tile into the other buffer, then wait ONLY for tile t's loads
            bf16* aw = Asw + (c ^ 1) * 16384;
            bf16* gw = Bgw + (c ^ 1) * 8192;
            bf16* uw = Buw + (c ^ 1) * 8192;
            const int kn = k0 + 64;
#pragma unroll
            for (int p = 0; p < 4; p++) gld_lds16(Ag  + kn + p * rstep, aw + p * 4096);
#pragma unroll
            for (int p = 0; p < 2; p++) gld_lds16(Bgg + kn + p * rstep, gw + p * 4096);
#pragma unroll
            for (int p = 0; p < 2; p++) gld_lds16(Bug + kn + p * rstep, uw + p * 4096);
            asm volatile("s_waitcnt vmcnt(8)" ::: "memory");
        } else {
            asm volatile("s_waitcnt vmcnt(0)" ::: "memory");
        }
        __builtin_amdgcn_s_barrier();          // buf[c] ready block-wide (ONLY barrier/tile)

        const bf16* ar = Asr0 + c * 16384;
        const bf16* gr = Bgr0 + c * 8192;
        const bf16* ur = Bur0 + c * 8192;

        bf16x8 a0[4], a1[4], g0[4], g1[4], u0[4], u1[4];
        // prefetch-ordered fragment loads; compiler inserts counted lgkm waits
#pragma unroll
        for (int i = 0; i < 4; i++) a0[i] = *(const bf16x8*)(ar + i * 1024);
#pragma unroll
        for (int j = 0; j < 4; j++) g0[j] = *(const bf16x8*)(gr + j * 1024);
#pragma unroll
        for (int j = 0; j < 4; j++) u0[j] = *(const bf16x8*)(ur + j * 1024);
#pragma unroll
        for (int i = 0; i < 4; i++) a1[i] = *(const bf16x8*)(ar + sx + i * 1024);

        __builtin_amdgcn_s_setprio(1);
#pragma unroll
        for (int i = 0; i < 4; i++)
#pragma unroll
            for (int j = 0; j < 4; j++)
                accg[i][j] = __builtin_amdgcn_mfma_f32_16x16x32_bf16(a0[i], g0[j], accg[i][j], 0, 0, 0);
        __builtin_amdgcn_s_setprio(0);
#pragma unroll
        for (int j = 0; j < 4; j++) g1[j] = *(const bf16x8*)(gr + sx + j * 1024);
        __builtin_amdgcn_s_setprio(1);
#pragma unroll
        for (int i = 0; i < 4; i++)
#pragma unroll
            for (int j = 0; j < 4; j++)
                accu[i][j] = __builtin_amdgcn_mfma_f32_16x16x32_bf16(a0[i], u0[j], accu[i][j], 0, 0, 0);
        __builtin_amdgcn_s_setprio(0);
#pragma unroll
        for (int j = 0; j < 4; j++) u1[j] = *(const bf16x8*)(ur + sx + j * 1024);
        __builtin_amdgcn_s_setprio(1);
#pragma unroll
        for (int i = 0; i < 4; i++)
#pragma unroll
            for (int j = 0; j < 4; j++)
                accg[i][j] = __builtin_amdgcn_mfma_f32_16x16x32_bf16(a1[i], g1[j], accg[i][j], 0, 0, 0);
#pragma unroll
        for (int i = 0; i < 4; i++)
#pragma unroll
            for (int j = 0; j < 4; j++)
                accu[i][j] = __builtin_amdgcn_mfma_f32_16x16x32_bf16(a1[i], u1[j], accu[i][j], 0, 0, 0);
        __builtin_amdgcn_s_setprio(0);

        c ^= 1;
    }

    // epilogue: per-wave LDS transpose -> silu(g)*u -> coalesced bf16 stores
    __syncthreads();
    float* Tw = (float*)smem + wave * 1088;
    const int rq = (lane >> 4) * 4;
#pragma unroll
    for (int i = 0; i < 4; i++) {
#pragma unroll
        for (int j = 0; j < 4; j++)
#pragma unroll
            for (int r = 0; r < 4; r++) {
                float g = accg[i][j][r];
                float u = accu[i][j][r];
                float h = (g / (1.0f + __expf(-g))) * u;
                Tw[(rq + r) * 68 + j * 16 + m16] = h;
            }
        __syncthreads();
#pragma unroll
        for (int s = 0; s < 4; s++) {
            int row = (lane >> 4) + 4 * s;
            f32x4 v = *(const f32x4*)(Tw + row * 68 + (m16 << 2));
            union { ushort u16[4]; uint2 d; } o;
            o.u16[0] = __bfloat16_as_ushort(__float2bfloat16(v[0]));
            o.u16[1] = __bfloat16_as_ushort(__float2bfloat16(v[1]));
            o.u16[2] = __bfloat16_as_ushort(__float2bfloat16(v[2]));
            o.u16[3] = __bfloat16_as_ushort(__float2bfloat16(v[3]));
            long grow = mBase + waveM + i * 16 + row;
            int  gcol = nBase + waveN + (m16 << 2);
            *(uint2*)(G + grow * D_FF + gcol) = o.d;
        }
        __syncthreads();
    }
}

// ---------------- down GEMM: Out[4096, 2048] = G @ Wd^T, fp32 out ----------------
// R2 structure (BK=64 dbuf, 64 KiB LDS, 2 blocks/CU, 8-slot XOR swizzle, counted
// vmcnt(8), one barrier per K-tile) + XCD swizzle: same-by blocks (share G panel,
// the 64MB operand) co-XCD.
__global__ __launch_bounds__(256, 2) void gemm_down(const bf16* __restrict__ A,
                                                    const bf16* __restrict__ B,
                                                    float* __restrict__ Out) {
    __shared__ alignas(16) char smem[65536];   // A: 2x16KB, B: 2x16KB; epilogue T = 17408 B
    bf16* As = (bf16*)smem;                    // [2][128][64]
    bf16* Bs = (bf16*)(smem + 32768);          // [2][128][64]

    const int t = threadIdx.x;
    // XCD swizzle: nwg = 16x32 = 512, 64 blocks per XCD chunk. w = (o&7)*64 + o>>3;
    // by = w>>4 in [4k, 4k+4), bx = w&15 -> the 16 blocks sharing each G panel co-XCD.
    const int o_ = blockIdx.y * 16 + blockIdx.x;
    const int w_ = (o_ & 7) * 64 + (o_ >> 3);
    const int mBase = (w_ >> 4) * 128;        // by
    const int nBase = (w_ & 15) * 128;        // bx
    const int K = D_FF;

    const int srow = t >> 3;                                  // 0..31 (32 rows per pass)
    const int colO = (((t & 7) - (srow & 7)) & 7) * 8;        // pre-swizzled global chunk
    const bf16* Ag = A + (long)(mBase + srow) * K + colO;
    const bf16* Bg = B + (long)(nBase + srow) * K + colO;
    const long rstep = (long)32 * K;

    f32x4 acc[4][4];
#pragma unroll
    for (int i = 0; i < 4; i++)
#pragma unroll
        for (int j = 0; j < 4; j++) {
            f32x4 z = {0.f, 0.f, 0.f, 0.f};
            acc[i][j] = z;
        }

    const int lane  = t & 63;
    const int wave  = t >> 6;                 // 0..3
    const int waveM = (wave & 1) * 64;
    const int waveN = (wave >> 1) * 64;
    const int m16   = lane & 15;
    const int s0    = (((lane >> 4) + (m16 & 7)) & 7) * 8;
    const int sx    = (s0 ^ 32) - s0;

    const bf16* Asr0 = As + (waveM + m16) * 64 + s0;
    const bf16* Bsr0 = Bs + (waveN + m16) * 64 + s0;

    bf16* Asw = As + t * 8;
    bf16* Bsw = Bs + t * 8;

    // prologue: stage K-tile 0 into buffer 0 (8 loads)
#pragma unroll
    for (int p = 0; p < 4; p++) gld_lds16(Ag + p * rstep, Asw + p * 2048);
#pragma unroll
    for (int p = 0; p < 4; p++) gld_lds16(Bg + p * rstep, Bsw + p * 2048);

    int c = 0;
    for (int k0 = 0; k0 < K; k0 += 64) {
        if (k0 + 64 < K) {
            bf16* aw = Asw + (c ^ 1) * 8192;
            bf16* bw = Bsw + (c ^ 1) * 8192;
            const int kn = k0 + 64;
#pragma unroll
            for (int p = 0; p < 4; p++) gld_lds16(Ag + kn + p * rstep, aw + p * 2048);
#pragma unroll
            for (int p = 0; p < 4; p++) gld_lds16(Bg + kn + p * rstep, bw + p * 2048);
            asm volatile("s_waitcnt vmcnt(8)" ::: "memory");
        } else {
            asm volatile("s_waitcnt vmcnt(0)" ::: "memory");
        }
        __builtin_amdgcn_s_barrier();          // buf[c] ready (ONLY barrier/tile)

        const bf16* ar = Asr0 + c * 8192;
        const bf16* br = Bsr0 + c * 8192;

        bf16x8 a0[4], b0[4], a1[4], b1[4];
#pragma unroll
        for (int i = 0; i < 4; i++) a0[i] = *(const bf16x8*)(ar + i * 1024);
#pragma unroll
        for (int j = 0; j < 4; j++) b0[j] = *(const bf16x8*)(br + j * 1024);
#pragma unroll
        for (int i = 0; i < 4; i++) a1[i] = *(const bf16x8*)(ar + sx + i * 1024);

        __builtin_amdgcn_s_setprio(1);
#pragma unroll
        for (int i = 0; i < 4; i++)
#pragma unroll
            for (int j = 0; j < 4; j++)
                acc[i][j] = __builtin_amdgcn_mfma_f32_16x16x32_bf16(a0[i], b0[j], acc[i][j], 0, 0, 0);
        __builtin_amdgcn_s_setprio(0);
#pragma unroll
        for (int j = 0; j < 4; j++) b1[j] = *(const bf16x8*)(br + sx + j * 1024);
        __builtin_amdgcn_s_setprio(1);
#pragma unroll
        for (int i = 0; i < 4; i++)
#pragma unroll
            for (int j = 0; j < 4; j++)
                acc[i][j] = __builtin_amdgcn_mfma_f32_16x16x32_bf16(a1[i], b1[j], acc[i][j], 0, 0, 0);
        __builtin_amdgcn_s_setprio(0);

        c ^= 1;
    }

    // epilogue: per-wave LDS transpose -> coalesced f32x4 stores (256 B segments)
    __syncthreads();
    float* Tw = (float*)smem + wave * 1088;
    const int rq = (lane >> 4) * 4;
#pragma unroll
    for (int i = 0; i < 4; i++) {
#pragma unroll
        for (int j = 0; j < 4; j++)
#pragma unroll
            for (int r = 0; r < 4; r++)
                Tw[(rq + r) * 68 + j * 16 + m16] = acc[i][j][r];
        __syncthreads();
#pragma unroll
        for (int s = 0; s < 4; s++) {
            int row = (lane >> 4) + 4 * s;
            f32x4 v = *(const f32x4*)(Tw + row * 68 + (m16 << 2));
            long grow = mBase + waveM + i * 16 + row;
            int  gcol = nBase + waveN + (m16 << 2);
            *(f32x4*)(Out + grow * D_MODEL + gcol) = v;
        }
        __syncthreads();
    }
}

extern "C" void kernel_launch(void* const* d_in, const int* in_sizes, int n_in,
                              void* d_out, int out_size, void* d_ws, size_t ws_size,
                              hipStream_t stream) {
    (void)in_sizes; (void)n_in; (void)out_size;
    const float* x     = (const float*)d_in[0];
    const float* lut_g = (const float*)d_in[1];
    const float* lut_u = (const float*)d_in[2];
    const float* lut_d = (const float*)d_in[3];
    const int*   wk_g  = (const int*)d_in[4];
    const int*   wk_u  = (const int*)d_in[5];
    const int*   wk_d  = (const int*)d_in[6];
    const float* sl_g  = (const float*)d_in[7];
    const float* sr_g  = (const float*)d_in[8];
    const float* sl_u  = (const float*)d_in[9];
    const float* sr_u  = (const float*)d_in[10];
    const float* sl_d  = (const float*)d_in[11];
    const float* sr_d  = (const float*)d_in[12];

    char* ws = (char*)d_ws;
    bf16* xb = (bf16*)(ws);                                   // 16 MB
    bf16* Wg = (bf16*)(ws + (size_t)16 * 1024 * 1024);        // 32 MB
    bf16* Wu = (bf16*)(ws + (size_t)48 * 1024 * 1024);        // 32 MB
    bf16* G  = (bf16*)(ws + (size_t)80 * 1024 * 1024);        // 64 MB
    const bool sepWd = ws_size >= (size_t)176 * 1024 * 1024;
    bf16* Wd = sepWd ? (bf16*)(ws + (size_t)144 * 1024 * 1024) : Wg;
    float* out = (float*)d_out;

    prep_kernel<<<dim3(sepWd ? 28672 : 20480), 256, 0, stream>>>(
        x, xb, wk_g, lut_g, sl_g, sr_g, Wg, wk_u, lut_u, sl_u, sr_u, Wu,
        wk_d, lut_d, sl_d, sr_d, sepWd ? Wd : nullptr);

    gemm_gateup<<<dim3(D_FF / 128, NTOK / 256), 512, 0, stream>>>(xb, Wg, Wu, G);

    if (!sepWd)
        dequant_kernel<<<dim3(D_MODEL * D_FF / 2048), 256, 0, stream>>>(wk_d, lut_d, sl_d, sr_d, Wd, 13);

    gemm_down<<<dim3(D_MODEL / 128, NTOK / 128), 256, 0, stream>>>(G, Wd, out);
}

// Round 5
// 592.866 us; speedup vs baseline: 1.0821x; 1.0192x over previous
//
#include <hip/hip_runtime.h>
#include <hip/hip_bf16.h>
#include <stdint.h>

#define D_MODEL 2048
#define D_FF    8192
#define NTOK    4096
#define WSCALE  0.02f

using bf16 = __hip_bfloat16;
typedef __bf16 bf16x8 __attribute__((ext_vector_type(8)));
typedef float  f32x4  __attribute__((ext_vector_type(4)));

// async global -> LDS, 16 B per lane (wave-uniform base + lane*16 layout)
__device__ __forceinline__ void gld_lds16(const bf16* g, bf16* l) {
    __builtin_amdgcn_global_load_lds((const __attribute__((address_space(1))) void*)g,
                                     (__attribute__((address_space(3))) void*)l,
                                     16, 0, 0);
}

// ---------------- standalone dequant (fallback when ws can't hold separate Wd) --------------
__global__ __launch_bounds__(256) void dequant_kernel(const int* __restrict__ walks,
                                                      const float* __restrict__ lut,
                                                      const float* __restrict__ sl,
                                                      const float* __restrict__ sr,
                                                      bf16* __restrict__ W,
                                                      int colsLog2) {
    __shared__ float slut[256];
    slut[threadIdx.x] = lut[threadIdx.x] * WSCALE;
    __syncthreads();
    long base = ((long)blockIdx.x * 256 + threadIdx.x) * 8;
    int r = (int)(base >> colsLog2);
    int c = (int)(base & ((1 << colsLog2) - 1));
    float s = sl[r];
    const int4* wp = (const int4*)(walks + base);
    int4 w0 = wp[0];
    int4 w1 = wp[1];
    float4 s0 = *(const float4*)(sr + c);
    float4 s1 = *(const float4*)(sr + c + 4);
    alignas(16) bf16 o[8];
    o[0] = __float2bfloat16(slut[w0.x] * s0.x * s);
    o[1] = __float2bfloat16(slut[w0.y] * s0.y * s);
    o[2] = __float2bfloat16(slut[w0.z] * s0.z * s);
    o[3] = __float2bfloat16(slut[w0.w] * s0.w * s);
    o[4] = __float2bfloat16(slut[w1.x] * s1.x * s);
    o[5] = __float2bfloat16(slut[w1.y] * s1.y * s);
    o[6] = __float2bfloat16(slut[w1.z] * s1.z * s);
    o[7] = __float2bfloat16(slut[w1.w] * s1.w * s);
    *(uint4*)(W + base) = *(const uint4*)o;
}

// ---------------- merged prep: x->bf16 + up to 3 dequants, one launch ----------------
__global__ __launch_bounds__(256) void prep_kernel(const float* __restrict__ x, bf16* __restrict__ xb,
    const int* __restrict__ wk_g, const float* __restrict__ lut_g,
    const float* __restrict__ sl_g, const float* __restrict__ sr_g, bf16* __restrict__ Wg,
    const int* __restrict__ wk_u, const float* __restrict__ lut_u,
    const float* __restrict__ sl_u, const float* __restrict__ sr_u, bf16* __restrict__ Wu,
    const int* __restrict__ wk_d, const float* __restrict__ lut_d,
    const float* __restrict__ sl_d, const float* __restrict__ sr_d, bf16* __restrict__ Wd) {
    const int t = threadIdx.x;
    const int b = blockIdx.x;
    if (b < 4096) {
        long base = ((long)b * 256 + t) * 8;
        float4 a = *(const float4*)(x + base);
        float4 v = *(const float4*)(x + base + 4);
        alignas(16) bf16 o[8];
        o[0] = __float2bfloat16(a.x); o[1] = __float2bfloat16(a.y);
        o[2] = __float2bfloat16(a.z); o[3] = __float2bfloat16(a.w);
        o[4] = __float2bfloat16(v.x); o[5] = __float2bfloat16(v.y);
        o[6] = __float2bfloat16(v.z); o[7] = __float2bfloat16(v.w);
        *(uint4*)(xb + base) = *(const uint4*)o;
        return;
    }
    const int* wk; const float* lut; const float* sl; const float* sr; bf16* W;
    int clog, bb;
    if (b < 12288)      { wk = wk_g; lut = lut_g; sl = sl_g; sr = sr_g; W = Wg; clog = 11; bb = b - 4096; }
    else if (b < 20480) { wk = wk_u; lut = lut_u; sl = sl_u; sr = sr_u; W = Wu; clog = 11; bb = b - 12288; }
    else                { wk = wk_d; lut = lut_d; sl = sl_d; sr = sr_d; W = Wd; clog = 13; bb = b - 20480; }
    __shared__ float slut[256];
    slut[t] = lut[t] * WSCALE;
    __syncthreads();
    long base = ((long)bb * 256 + t) * 8;
    int r = (int)(base >> clog);
    int c = (int)(base & ((1 << clog) - 1));
    float s = sl[r];
    const int4* wp = (const int4*)(wk + base);
    int4 w0 = wp[0];
    int4 w1 = wp[1];
    float4 s0 = *(const float4*)(sr + c);
    float4 s1 = *(const float4*)(sr + c + 4);
    alignas(16) bf16 o[8];
    o[0] = __float2bfloat16(slut[w0.x] * s0.x * s);
    o[1] = __float2bfloat16(slut[w0.y] * s0.y * s);
    o[2] = __float2bfloat16(slut[w0.z] * s0.z * s);
    o[3] = __float2bfloat16(slut[w0.w] * s0.w * s);
    o[4] = __float2bfloat16(slut[w1.x] * s1.x * s);
    o[5] = __float2bfloat16(slut[w1.y] * s1.y * s);
    o[6] = __float2bfloat16(slut[w1.z] * s1.z * s);
    o[7] = __float2bfloat16(slut[w1.w] * s1.w * s);
    *(uint4*)(W + base) = *(const uint4*)o;
}

// LDS XOR swizzle, BK=64 (8 chunks of 8 bf16 per 128 B row):
//   chunk c of row r at slot (c + r) & 7.  Writer: linear LDS dest, inverse-swizzled
//   GLOBAL source (colO).  Reader: s0 = ((lane>>4)+(m16&7))&7 slot; ks=1 slot = slot^4
//   via sx = (s0^32)-s0.
//
// R5 change (ONLY change vs R4): the K-loop barrier is emitted as OPAQUE INLINE ASM
// fused with the counted vmcnt ("s_waitcnt vmcnt(8); s_barrier" in one asm block).
// Hypothesis (from the ~1900 cyc/tile unexplained gap, constant across R1/R2/R4
// schedules): hipcc's waitcnt pass treats global_load_lds as a pending LDS write and
// attaches a conservative vmcnt(0) drain to __builtin_amdgcn_s_barrier(), nullifying
// the counted vmcnt(8) and synchronously exposing the just-issued stage's HBM latency
// every tile. An asm barrier is invisible to that pass. Correctness unchanged: each
// wave's own vmcnt(8) retires its tile-t stage contribution before it arrives at the
// barrier; barrier ∧ per-wave count ⇒ buf[c] valid block-wide.
// NOTE: epilogue acc loops MUST stay fully unrolled — runtime idx -> scratch spill.

// ---------------- fused gate+up GEMM, 256x128 tile, BK=64, 1-barrier pipelined K-tile -------
__global__ __launch_bounds__(512, 2) void gemm_gateup(const bf16* __restrict__ A,
                                                      const bf16* __restrict__ Bg_,
                                                      const bf16* __restrict__ Bu_,
                                                      bf16* __restrict__ G) {
    __shared__ alignas(16) char smem[131072];
    bf16* As  = (bf16*)smem;                 // [2][256][64] : 2 x 32 KB
    bf16* Bgs = (bf16*)(smem + 65536);       // [2][128][64] : 2 x 16 KB
    bf16* Bus = (bf16*)(smem + 98304);       // [2][128][64] : 2 x 16 KB

    const int t = threadIdx.x;
    // XCD swizzle (kept from R4: neutral-to-positive, zero cost): same-bx co-XCD.
    const int o_ = blockIdx.y * 64 + blockIdx.x;
    const int w_ = (o_ & 7) * 128 + (o_ >> 3);
    const int mBase = (w_ & 15) * 256;       // by
    const int nBase = (w_ >> 4) * 128;       // bx
    const int K = D_MODEL;

    const int srow = t >> 3;                                  // 0..63 (64 rows per pass)
    const int colO = (((t & 7) - (srow & 7)) & 7) * 8;        // pre-swizzled global chunk
    const bf16* Ag  = A   + (long)(mBase + srow) * K + colO;
    const bf16* Bgg = Bg_ + (long)(nBase + srow) * K + colO;
    const bf16* Bug = Bu_ + (long)(nBase + srow) * K + colO;
    const long rstep = (long)64 * K;

    f32x4 accg[4][4], accu[4][4];
#pragma unroll
    for (int i = 0; i < 4; i++)
#pragma unroll
        for (int j = 0; j < 4; j++) {
            f32x4 z = {0.f, 0.f, 0.f, 0.f};
            accg[i][j] = z; accu[i][j] = z;
        }

    const int lane  = t & 63;
    const int wave  = t >> 6;                 // 0..7
    const int waveM = (wave >> 1) * 64;       // 0,64,128,192
    const int waveN = (wave & 1) * 64;        // 0,64
    const int m16   = lane & 15;
    const int s0    = (((lane >> 4) + (m16 & 7)) & 7) * 8;
    const int sx    = (s0 ^ 32) - s0;         // chunk+4 (mod 8) for ks=1

    const bf16* Asr0 = As  + (waveM + m16) * 64 + s0;
    const bf16* Bgr0 = Bgs + (waveN + m16) * 64 + s0;
    const bf16* Bur0 = Bus + (waveN + m16) * 64 + s0;

    bf16* Asw = As  + t * 8;
    bf16* Bgw = Bgs + t * 8;
    bf16* Buw = Bus + t * 8;

    // prologue: stage K-tile 0 into buffer 0 (8 loads)
#pragma unroll
    for (int p = 0; p < 4; p++) gld_lds16(Ag  + p * rstep, Asw + p * 4096);
#pragma unroll
    for (int p = 0; p < 2; p++) gld_lds16(Bgg + p * rstep, Bgw + p * 4096);
#pragma unroll
    for (int p = 0; p < 2; p++) gld_lds16(Bug + p * rstep, Buw + p * 4096);

    int c = 0;
    for (int k0 = 0; k0 < K; k0 += 64) {
        if (k0 + 64 < K) {
            // stage next K-tile into the other buffer, then wait ONLY for tile t's loads
            bf16* aw = Asw + (c ^ 1) * 16384;
            bf16* gw = Bgw + (c ^ 1) * 8192;
            bf16* uw = Buw + (c ^ 1) * 8192;
            const int kn = k0 + 64;
#pragma unroll
            for (int p = 0; p < 4; p++) gld_lds16(Ag  + kn + p * rstep, aw + p * 4096);
#pragma unroll
            for (int p = 0; p < 2; p++) gld_lds16(Bgg + kn + p * rstep, gw + p * 4096);
#pragma unroll
            for (int p = 0; p < 2; p++) gld_lds16(Bug + kn + p * rstep, uw + p * 4096);
            asm volatile("s_waitcnt vmcnt(8)\n\ts_barrier" ::: "memory");
        } else {
            asm volatile("s_waitcnt vmcnt(0)\n\ts_barrier" ::: "memory");
        }
        // buf[c] ready block-wide (ONLY barrier/tile; opaque to the waitcnt pass)

        const bf16* ar = Asr0 + c * 16384;
        const bf16* gr = Bgr0 + c * 8192;
        const bf16* ur = Bur0 + c * 8192;

        bf16x8 a0[4], a1[4], g0[4], g1[4], u0[4], u1[4];
        // prefetch-ordered fragment loads; compiler inserts counted lgkm waits
#pragma unroll
        for (int i = 0; i < 4; i++) a0[i] = *(const bf16x8*)(ar + i * 1024);
#pragma unroll
        for (int j = 0; j < 4; j++) g0[j] = *(const bf16x8*)(gr + j * 1024);
#pragma unroll
        for (int j = 0; j < 4; j++) u0[j] = *(const bf16x8*)(ur + j * 1024);
#pragma unroll
        for (int i = 0; i < 4; i++) a1[i] = *(const bf16x8*)(ar + sx + i * 1024);

        __builtin_amdgcn_s_setprio(1);
#pragma unroll
        for (int i = 0; i < 4; i++)
#pragma unroll
            for (int j = 0; j < 4; j++)
                accg[i][j] = __builtin_amdgcn_mfma_f32_16x16x32_bf16(a0[i], g0[j], accg[i][j], 0, 0, 0);
        __builtin_amdgcn_s_setprio(0);
#pragma unroll
        for (int j = 0; j < 4; j++) g1[j] = *(const bf16x8*)(gr + sx + j * 1024);
        __builtin_amdgcn_s_setprio(1);
#pragma unroll
        for (int i = 0; i < 4; i++)
#pragma unroll
            for (int j = 0; j < 4; j++)
                accu[i][j] = __builtin_amdgcn_mfma_f32_16x16x32_bf16(a0[i], u0[j], accu[i][j], 0, 0, 0);
        __builtin_amdgcn_s_setprio(0);
#pragma unroll
        for (int j = 0; j < 4; j++) u1[j] = *(const bf16x8*)(ur + sx + j * 1024);
        __builtin_amdgcn_s_setprio(1);
#pragma unroll
        for (int i = 0; i < 4; i++)
#pragma unroll
            for (int j = 0; j < 4; j++)
                accg[i][j] = __builtin_amdgcn_mfma_f32_16x16x32_bf16(a1[i], g1[j], accg[i][j], 0, 0, 0);
#pragma unroll
        for (int i = 0; i < 4; i++)
#pragma unroll
            for (int j = 0; j < 4; j++)
                accu[i][j] = __builtin_amdgcn_mfma_f32_16x16x32_bf16(a1[i], u1[j], accu[i][j], 0, 0, 0);
        __builtin_amdgcn_s_setprio(0);

        c ^= 1;
    }

    // epilogue: per-wave LDS transpose -> silu(g)*u -> coalesced bf16 stores
    __syncthreads();
    float* Tw = (float*)smem + wave * 1088;
    const int rq = (lane >> 4) * 4;
#pragma unroll
    for (int i = 0; i < 4; i++) {
#pragma unroll
        for (int j = 0; j < 4; j++)
#pragma unroll
            for (int r = 0; r < 4; r++) {
                float g = accg[i][j][r];
                float u = accu[i][j][r];
                float h = (g / (1.0f + __expf(-g))) * u;
                Tw[(rq + r) * 68 + j * 16 + m16] = h;
            }
        __syncthreads();
#pragma unroll
        for (int s = 0; s < 4; s++) {
            int row = (lane >> 4) + 4 * s;
            f32x4 v = *(const f32x4*)(Tw + row * 68 + (m16 << 2));
            union { ushort u16[4]; uint2 d; } o;
            o.u16[0] = __bfloat16_as_ushort(__float2bfloat16(v[0]));
            o.u16[1] = __bfloat16_as_ushort(__float2bfloat16(v[1]));
            o.u16[2] = __bfloat16_as_ushort(__float2bfloat16(v[2]));
            o.u16[3] = __bfloat16_as_ushort(__float2bfloat16(v[3]));
            long grow = mBase + waveM + i * 16 + row;
            int  gcol = nBase + waveN + (m16 << 2);
            *(uint2*)(G + grow * D_FF + gcol) = o.d;
        }
        __syncthreads();
    }
}

// ---------------- down GEMM: Out[4096, 2048] = G @ Wd^T, fp32 out ----------------
// R4 structure (BK=64 dbuf, 64 KiB LDS, 2 blocks/CU, 8-slot XOR swizzle, counted
// vmcnt(8), one barrier per K-tile, XCD swizzle) with the R5 asm-fused barrier.
__global__ __launch_bounds__(256, 2) void gemm_down(const bf16* __restrict__ A,
                                                    const bf16* __restrict__ B,
                                                    float* __restrict__ Out) {
    __shared__ alignas(16) char smem[65536];   // A: 2x16KB, B: 2x16KB; epilogue T = 17408 B
    bf16* As = (bf16*)smem;                    // [2][128][64]
    bf16* Bs = (bf16*)(smem + 32768);          // [2][128][64]

    const int t = threadIdx.x;
    // XCD swizzle: same-by co-XCD (G panel sharing).
    const int o_ = blockIdx.y * 16 + blockIdx.x;
    const int w_ = (o_ & 7) * 64 + (o_ >> 3);
    const int mBase = (w_ >> 4) * 128;        // by
    const int nBase = (w_ & 15) * 128;        // bx
    const int K = D_FF;

    const int srow = t >> 3;                                  // 0..31 (32 rows per pass)
    const int colO = (((t & 7) - (srow & 7)) & 7) * 8;        // pre-swizzled global chunk
    const bf16* Ag = A + (long)(mBase + srow) * K + colO;
    const bf16* Bg = B + (long)(nBase + srow) * K + colO;
    const long rstep = (long)32 * K;

    f32x4 acc[4][4];
#pragma unroll
    for (int i = 0; i < 4; i++)
#pragma unroll
        for (int j = 0; j < 4; j++) {
            f32x4 z = {0.f, 0.f, 0.f, 0.f};
            acc[i][j] = z;
        }

    const int lane  = t & 63;
    const int wave  = t >> 6;                 // 0..3
    const int waveM = (wave & 1) * 64;
    const int waveN = (wave >> 1) * 64;
    const int m16   = lane & 15;
    const int s0    = (((lane >> 4) + (m16 & 7)) & 7) * 8;
    const int sx    = (s0 ^ 32) - s0;

    const bf16* Asr0 = As + (waveM + m16) * 64 + s0;
    const bf16* Bsr0 = Bs + (waveN + m16) * 64 + s0;

    bf16* Asw = As + t * 8;
    bf16* Bsw = Bs + t * 8;

    // prologue: stage K-tile 0 into buffer 0 (8 loads)
#pragma unroll
    for (int p = 0; p < 4; p++) gld_lds16(Ag + p * rstep, Asw + p * 2048);
#pragma unroll
    for (int p = 0; p < 4; p++) gld_lds16(Bg + p * rstep, Bsw + p * 2048);

    int c = 0;
    for (int k0 = 0; k0 < K; k0 += 64) {
        if (k0 + 64 < K) {
            bf16* aw = Asw + (c ^ 1) * 8192;
            bf16* bw = Bsw + (c ^ 1) * 8192;
            const int kn = k0 + 64;
#pragma unroll
            for (int p = 0; p < 4; p++) gld_lds16(Ag + kn + p * rstep, aw + p * 2048);
#pragma unroll
            for (int p = 0; p < 4; p++) gld_lds16(Bg + kn + p * rstep, bw + p * 2048);
            asm volatile("s_waitcnt vmcnt(8)\n\ts_barrier" ::: "memory");
        } else {
            asm volatile("s_waitcnt vmcnt(0)\n\ts_barrier" ::: "memory");
        }
        // buf[c] ready (ONLY barrier/tile; opaque to the waitcnt pass)

        const bf16* ar = Asr0 + c * 8192;
        const bf16* br = Bsr0 + c * 8192;

        bf16x8 a0[4], b0[4], a1[4], b1[4];
#pragma unroll
        for (int i = 0; i < 4; i++) a0[i] = *(const bf16x8*)(ar + i * 1024);
#pragma unroll
        for (int j = 0; j < 4; j++) b0[j] = *(const bf16x8*)(br + j * 1024);
#pragma unroll
        for (int i = 0; i < 4; i++) a1[i] = *(const bf16x8*)(ar + sx + i * 1024);

        __builtin_amdgcn_s_setprio(1);
#pragma unroll
        for (int i = 0; i < 4; i++)
#pragma unroll
            for (int j = 0; j < 4; j++)
                acc[i][j] = __builtin_amdgcn_mfma_f32_16x16x32_bf16(a0[i], b0[j], acc[i][j], 0, 0, 0);
        __builtin_amdgcn_s_setprio(0);
#pragma unroll
        for (int j = 0; j < 4; j++) b1[j] = *(const bf16x8*)(br + sx + j * 1024);
        __builtin_amdgcn_s_setprio(1);
#pragma unroll
        for (int i = 0; i < 4; i++)
#pragma unroll
            for (int j = 0; j < 4; j++)
                acc[i][j] = __builtin_amdgcn_mfma_f32_16x16x32_bf16(a1[i], b1[j], acc[i][j], 0, 0, 0);
        __builtin_amdgcn_s_setprio(0);

        c ^= 1;
    }

    // epilogue: per-wave LDS transpose -> coalesced f32x4 stores (256 B segments)
    __syncthreads();
    float* Tw = (float*)smem + wave * 1088;
    const int rq = (lane >> 4) * 4;
#pragma unroll
    for (int i = 0; i < 4; i++) {
#pragma unroll
        for (int j = 0; j < 4; j++)
#pragma unroll
            for (int r = 0; r < 4; r++)
                Tw[(rq + r) * 68 + j * 16 + m16] = acc[i][j][r];
        __syncthreads();
#pragma unroll
        for (int s = 0; s < 4; s++) {
            int row = (lane >> 4) + 4 * s;
            f32x4 v = *(const f32x4*)(Tw + row * 68 + (m16 << 2));
            long grow = mBase + waveM + i * 16 + row;
            int  gcol = nBase + waveN + (m16 << 2);
            *(f32x4*)(Out + grow * D_MODEL + gcol) = v;
        }
        __syncthreads();
    }
}

extern "C" void kernel_launch(void* const* d_in, const int* in_sizes, int n_in,
                              void* d_out, int out_size, void* d_ws, size_t ws_size,
                              hipStream_t stream) {
    (void)in_sizes; (void)n_in; (void)out_size;
    const float* x     = (const float*)d_in[0];
    const float* lut_g = (const float*)d_in[1];
    const float* lut_u = (const float*)d_in[2];
    const float* lut_d = (const float*)d_in[3];
    const int*   wk_g  = (const int*)d_in[4];
    const int*   wk_u  = (const int*)d_in[5];
    const int*   wk_d  = (const int*)d_in[6];
    const float* sl_g  = (const float*)d_in[7];
    const float* sr_g  = (const float*)d_in[8];
    const float* sl_u  = (const float*)d_in[9];
    const float* sr_u  = (const float*)d_in[10];
    const float* sl_d  = (const float*)d_in[11];
    const float* sr_d  = (const float*)d_in[12];

    char* ws = (char*)d_ws;
    bf16* xb = (bf16*)(ws);                                   // 16 MB
    bf16* Wg = (bf16*)(ws + (size_t)16 * 1024 * 1024);        // 32 MB
    bf16* Wu = (bf16*)(ws + (size_t)48 * 1024 * 1024);        // 32 MB
    bf16* G  = (bf16*)(ws + (size_t)80 * 1024 * 1024);        // 64 MB
    const bool sepWd = ws_size >= (size_t)176 * 1024 * 1024;
    bf16* Wd = sepWd ? (bf16*)(ws + (size_t)144 * 1024 * 1024) : Wg;
    float* out = (float*)d_out;

    prep_kernel<<<dim3(sepWd ? 28672 : 20480), 256, 0, stream>>>(
        x, xb, wk_g, lut_g, sl_g, sr_g, Wg, wk_u, lut_u, sl_u, sr_u, Wu,
        wk_d, lut_d, sl_d, sr_d, sepWd ? Wd : nullptr);

    gemm_gateup<<<dim3(D_FF / 128, NTOK / 256), 512, 0, stream>>>(xb, Wg, Wu, G);

    if (!sepWd)
        dequant_kernel<<<dim3(D_MODEL * D_FF / 2048), 256, 0, stream>>>(wk_d, lut_d, sl_d, sr_d, Wd, 13);

    gemm_down<<<dim3(D_MODEL / 128, NTOK / 128), 256, 0, stream>>>(G, Wd, out);
}